// Round 2
// baseline (102.977 us; speedup 1.0000x reference)
//
#include <hip/hip_runtime.h>
#include <math.h>

// 256-point FFT = 16x16 four-step Cooley-Tukey, one batch per 16 lanes.
// All global I/O is float4 (dwordx4); the stride-16 sample permutation,
// the mid transpose, and the output re-layout all go through a
// wave-private LDS region -> no __syncthreads anywhere.

#define NB 16   // batches per 256-thread block
#define S  552  // per-batch LDS stride in floats: %32==8 (bank shift), *4%16==0 (f4 align)

__device__ __forceinline__ void wave_fence() {
    // Compiler-only ordering fence; LDS ops of a wave execute in order in HW.
    __builtin_amdgcn_wave_barrier();
}

__device__ __forceinline__ void fft16(float re[16], float im[16]) {
    // 4-bit bit-reversal permutation (swap i < rev(i))
    {
        float tr, ti;
#define SWP(a, b) tr = re[a]; re[a] = re[b]; re[b] = tr; ti = im[a]; im[a] = im[b]; im[b] = ti;
        SWP(1, 8) SWP(2, 4) SWP(3, 12) SWP(5, 10) SWP(7, 14) SWP(11, 13)
#undef SWP
    }
    const float C[8] = { 1.0f,  0.92387953251f,  0.70710678119f,  0.38268343236f,
                         0.0f, -0.38268343236f, -0.70710678119f, -0.92387953251f };
    const float S16[8] = { 0.0f, -0.38268343236f, -0.70710678119f, -0.92387953251f,
                          -1.0f, -0.92387953251f, -0.70710678119f, -0.38268343236f };
#pragma unroll
    for (int s = 1; s <= 4; ++s) {
        const int len = 1 << s;
        const int half = len >> 1;
        const int step = 16 >> s;
#pragma unroll
        for (int i = 0; i < 16; i += len) {
#pragma unroll
            for (int j = 0; j < half; ++j) {
                const float wr = C[j * step];
                const float wi = S16[j * step];
                const int p = i + j;
                const int q = i + j + half;
                const float vr = re[q] * wr - im[q] * wi;
                const float vi = re[q] * wi + im[q] * wr;
                const float ur = re[p], ui = im[p];
                re[p] = ur + vr; im[p] = ui + vi;
                re[q] = ur - vr; im[q] = ui - vi;
            }
        }
    }
}

__global__ __launch_bounds__(256) void fft256_kernel(const float4* __restrict__ x4,
                                                     float4* __restrict__ o4) {
    __shared__ __align__(16) float lds[NB * S];

    const int tid = threadIdx.x;
    const int sub = tid >> 4;   // batch within block (wave = 4 consecutive subs)
    const int t   = tid & 15;
    const long b  = (long)blockIdx.x * NB + sub;

    float* L = lds + sub * S;   // wave-private region

    // ---- Phase A: global float4 -> LDS, linear layout r[0..255] i[256..511]
    const float4* src = x4 + b * 128;
#pragma unroll
    for (int j = 0; j < 8; ++j) {
        *(float4*)(L + 4 * (t + 16 * j)) = src[t + 16 * j];
    }
    wave_fence();

    // ---- Phase B: thread t gathers x[16a + t] (stride-16), FFT16 over a
    float re[16], im[16];
#pragma unroll
    for (int i = 0; i < 16; ++i) {
        re[i] = L[t + 16 * i];
        im[i] = L[256 + t + 16 * i];
    }
    fft16(re, im);
    wave_fence();

    // ---- Phase C: twiddle W_256^{t*k}, write transposed tile [t][k], pad 17
#pragma unroll
    for (int k = 0; k < 16; ++k) {
        float sv, cv;
        __sincosf(-6.283185307179586f * (float)(t * k) * (1.0f / 256.0f), &sv, &cv);
        L[17 * t + k]       = re[k] * cv - im[k] * sv;
        L[272 + 17 * t + k] = re[k] * sv + im[k] * cv;
    }
    wave_fence();

    // ---- Phase D: read column [n][t], second FFT16 over n
#pragma unroll
    for (int n = 0; n < 16; ++n) {
        re[n] = L[17 * n + t];
        im[n] = L[272 + 17 * n + t];
    }
    fft16(re, im);
    wave_fence();

    // ---- Phase E: scatter X[t + 16d] into linear output layout in LDS
#pragma unroll
    for (int k = 0; k < 16; ++k) {
        L[t + 16 * k]       = re[k];
        L[256 + t + 16 * k] = im[k];
    }
    wave_fence();

    // ---- Phase F: LDS -> global, float4 stores
    float4* dst = o4 + b * 128;
#pragma unroll
    for (int j = 0; j < 8; ++j) {
        dst[t + 16 * j] = *(const float4*)(L + 4 * (t + 16 * j));
    }
}

extern "C" void kernel_launch(void* const* d_in, const int* in_sizes, int n_in,
                              void* d_out, int out_size, void* d_ws, size_t ws_size,
                              hipStream_t stream) {
    (void)d_ws; (void)ws_size; (void)n_in; (void)out_size;
    const float4* x = (const float4*)d_in[0];
    float4* out = (float4*)d_out;
    const int batches = in_sizes[0] / 512;   // 131072
    const int grid = batches / NB;           // 8192 blocks
    fft256_kernel<<<grid, 256, 0, stream>>>(x, out);
}